// Round 7
// baseline (868.887 us; speedup 1.0000x reference)
//
#include <hip/hip_runtime.h>
#include <math.h>

typedef short short8v __attribute__((ext_vector_type(8)));
typedef float f32x4 __attribute__((ext_vector_type(4)));
typedef unsigned short ushort4v __attribute__((ext_vector_type(4)));

#define T_TOK 8192
#define DDIM 1024
#define HDIM 4096
#define NE 8
#define CCAP 2150
#define CPAD 2304   // 18 * 128

__device__ __forceinline__ unsigned short f2bf(float f) {
  union { float f; unsigned u; } a; a.f = f;
  unsigned r = a.u + 0x7fffu + ((a.u >> 16) & 1u);   // RNE
  return (unsigned short)(r >> 16);
}
__device__ __forceinline__ float bf2f(unsigned short h) {
  union { unsigned u; float f; } a; a.u = ((unsigned)h) << 16;
  return a.f;
}

#define GLOAD_LDS16(gp, lp)                                                   \
  __builtin_amdgcn_global_load_lds(                                           \
      (const __attribute__((address_space(1))) void*)(gp),                    \
      (__attribute__((address_space(3))) void*)(lp), 16, 0, 0)

// ---------------------------------------------------------------- router ---
__global__ __launch_bounds__(256) void router_kernel(
    const float* __restrict__ x, const float* __restrict__ Wg,
    int2* __restrict__ topi, float2* __restrict__ topv,
    float* __restrict__ blkimp) {
  __shared__ float wg[NE * DDIM];
  __shared__ float gsh[4][NE];
  int tid = threadIdx.x;
  for (int i = tid; i < NE * DDIM / 4; i += 256)
    ((float4*)wg)[i] = ((const float4*)Wg)[i];
  __syncthreads();
  int w = tid >> 6, lane = tid & 63;
  int t = blockIdx.x * 4 + w;
  const float* xr = x + (size_t)t * DDIM;
  float p[NE] = {0.f, 0.f, 0.f, 0.f, 0.f, 0.f, 0.f, 0.f};
#pragma unroll
  for (int j = 0; j < 16; ++j) {
    float xv = xr[lane + 64 * j];
#pragma unroll
    for (int e = 0; e < NE; ++e)
      p[e] = fmaf(xv, wg[e * DDIM + lane + 64 * j], p[e]);
  }
#pragma unroll
  for (int e = 0; e < NE; ++e) {
#pragma unroll
    for (int off = 32; off > 0; off >>= 1) p[e] += __shfl_xor(p[e], off, 64);
  }
  float mx = p[0];
#pragma unroll
  for (int e = 1; e < NE; ++e) mx = fmaxf(mx, p[e]);
  float g[NE];
  float s = 0.f;
#pragma unroll
  for (int e = 0; e < NE; ++e) { g[e] = expf(p[e] - mx); s += g[e]; }
  float inv = 1.0f / s;
#pragma unroll
  for (int e = 0; e < NE; ++e) g[e] *= inv;
  int i0 = 0; float v0 = g[0];
#pragma unroll
  for (int e = 1; e < NE; ++e) if (g[e] > v0) { v0 = g[e]; i0 = e; }
  int i1 = -1; float v1 = -1.0f;
#pragma unroll
  for (int e = 0; e < NE; ++e)
    if (e != i0 && g[e] > v1) { v1 = g[e]; i1 = e; }
  if (lane == 0) {
    topi[t] = make_int2(i0, i1);
    topv[t] = make_float2(v0, v1);
#pragma unroll
    for (int e = 0; e < NE; ++e) gsh[w][e] = g[e];
  }
  __syncthreads();
  if (tid < NE)
    blkimp[blockIdx.x * NE + tid] =
        gsh[0][tid] + gsh[1][tid] + gsh[2][tid] + gsh[3][tid];
}

// ---------------------------------------------- FCFS dispatch + losses -----
__global__ __launch_bounds__(256) void dispatch_kernel(
    const int2* __restrict__ topi, const float2* __restrict__ topv,
    const float* __restrict__ blkimp, int2* __restrict__ posmj,
    float2* __restrict__ wmaj, float* __restrict__ tail) {
  __shared__ unsigned char eid[2 * T_TOK];
  __shared__ unsigned short possm[2 * T_TOK];
  __shared__ int cnt_sh[NE];
  __shared__ float part[32][NE];
  int tid = threadIdx.x;
  for (int i = tid; i < T_TOK; i += 256) {
    int2 ti = topi[i];
    eid[i] = (unsigned char)ti.x;
    eid[T_TOK + i] = (unsigned char)ti.y;
  }
  __syncthreads();
  if (tid < 64) {
    int lane = tid;
    unsigned long long low = (1ull << lane) - 1ull;
    int c0 = 0, c1 = 0, c2 = 0, c3 = 0, c4 = 0, c5 = 0, c6 = 0, c7 = 0;
    for (int base = 0; base < 2 * T_TOK; base += 64) {
      int e = eid[base + lane];
      unsigned long long m0 = __ballot(e == 0);
      unsigned long long m1 = __ballot(e == 1);
      unsigned long long m2 = __ballot(e == 2);
      unsigned long long m3 = __ballot(e == 3);
      unsigned long long m4 = __ballot(e == 4);
      unsigned long long m5 = __ballot(e == 5);
      unsigned long long m6 = __ballot(e == 6);
      unsigned long long m7 = __ballot(e == 7);
      int rank = 0;
      if (e == 0) rank = c0 + __popcll(m0 & low);
      if (e == 1) rank = c1 + __popcll(m1 & low);
      if (e == 2) rank = c2 + __popcll(m2 & low);
      if (e == 3) rank = c3 + __popcll(m3 & low);
      if (e == 4) rank = c4 + __popcll(m4 & low);
      if (e == 5) rank = c5 + __popcll(m5 & low);
      if (e == 6) rank = c6 + __popcll(m6 & low);
      if (e == 7) rank = c7 + __popcll(m7 & low);
      possm[base + lane] = (unsigned short)((rank < CCAP) ? rank : CCAP);
      c0 += __popcll(m0); c1 += __popcll(m1); c2 += __popcll(m2);
      c3 += __popcll(m3); c4 += __popcll(m4); c5 += __popcll(m5);
      c6 += __popcll(m6); c7 += __popcll(m7);
    }
    if (lane == 0) {
      cnt_sh[0] = c0; cnt_sh[1] = c1; cnt_sh[2] = c2; cnt_sh[3] = c3;
      cnt_sh[4] = c4; cnt_sh[5] = c5; cnt_sh[6] = c6; cnt_sh[7] = c7;
    }
  }
  __syncthreads();
  for (int t = tid; t < T_TOK; t += 256) {
    int p0 = possm[t], p1 = possm[T_TOK + t];
    float2 tv = topv[t];
    float w0 = (p0 < CCAP) ? tv.x : 0.0f;
    float w1 = (p1 < CCAP) ? tv.y : 0.0f;
    float s = w0 + w1;
    if (s > 0.0f) { w0 /= s; w1 /= s; }
    posmj[t] = make_int2(p0, p1);
    wmaj[t] = make_float2(w0, w1);
  }
  {
    int sl = tid >> 3, e8 = tid & 7;
    float s = 0.f;
    for (int b = sl; b < 2048; b += 32) s += blkimp[b * NE + e8];
    part[sl][e8] = s;
  }
  __syncthreads();
  if (tid == 0) {
    float imp[NE], te[NE];
    for (int e = 0; e < NE; ++e) {
      float s = 0.f;
      for (int j = 0; j < 32; ++j) s += part[j][e];
      imp[e] = s;
      int c = cnt_sh[e];
      te[e] = (float)(c < CCAP ? c : CCAP);
    }
    float mi = 0.f, mt = 0.f;
    for (int e = 0; e < NE; ++e) { mi += imp[e]; mt += te[e]; }
    mi *= 0.125f; mt *= 0.125f;
    float vi = 0.f, vt = 0.f;
    for (int e = 0; e < NE; ++e) {
      vi += (imp[e] - mi) * (imp[e] - mi);
      vt += (te[e] - mt) * (te[e] - mt);
    }
    vi *= 0.125f; vt *= 0.125f;
    float ai = sqrtf(vi) / (mi + 1e-6f);
    float at = sqrtf(vt) / (mt + 1e-6f);
    tail[0] = 0.5f * (ai * ai + at * at);
    tail[1] = at * at;
  }
}

// --------------------------------------------------------------- scatter ---
__global__ __launch_bounds__(256) void scatter_kernel(
    const float* __restrict__ x, const int2* __restrict__ topi,
    const int2* __restrict__ posmj, unsigned short* __restrict__ ein) {
  int tid = threadIdx.x;
  int gid = blockIdx.x * 4 + (tid >> 6);
  int lane = tid & 63;
  int t = gid >> 1, k = gid & 1;
  int2 pp = posmj[t];
  int p = k ? pp.y : pp.x;
  if (p >= CCAP) return;
  int2 ii = topi[t];
  int e = k ? ii.y : ii.x;
  const float4* src = (const float4*)(x + (size_t)t * DDIM);
  unsigned short* dst = ein + ((size_t)e * CPAD + p) * DDIM;
#pragma unroll
  for (int j = 0; j < 4; ++j) {
    int c = j * 64 + lane;
    float4 v = src[c];
    ushort4v o;
    o.x = f2bf(v.x); o.y = f2bf(v.y); o.z = f2bf(v.z); o.w = f2bf(v.w);
    *(ushort4v*)(dst + (size_t)c * 4) = o;
  }
}

// ------------------------------------------------- weight transpose+cvt ----
__global__ __launch_bounds__(256) void transpose_cvt_kernel(
    const float* __restrict__ W, unsigned short* __restrict__ WT, int R,
    int Cc) {
  __shared__ unsigned short tile[64][72];
  int rt = R >> 6, ct = Cc >> 6;
  int per_e = rt * ct;
  int e = blockIdx.x / per_e;
  int rem = blockIdx.x % per_e;
  int tr = rem % rt, tc = rem / rt;
  int r0 = tr << 6, c0 = tc << 6;
  const float* We = W + (size_t)e * R * Cc;
  unsigned short* WTe = WT + (size_t)e * R * Cc;
  int tid = threadIdx.x;
  {
    int rl = tid >> 2, cb = (tid & 3) << 4;
    const float* src = We + (size_t)(r0 + rl) * Cc + c0 + cb;
#pragma unroll
    for (int j = 0; j < 16; j += 4) {
      float4 v = *(const float4*)(src + j);
      tile[rl][cb + j + 0] = f2bf(v.x);
      tile[rl][cb + j + 1] = f2bf(v.y);
      tile[rl][cb + j + 2] = f2bf(v.z);
      tile[rl][cb + j + 3] = f2bf(v.w);
    }
  }
  __syncthreads();
  {
    int cl = tid >> 2, rb = (tid & 3) << 4;
    unsigned short* dst = WTe + (size_t)(c0 + cl) * R + r0 + rb;
#pragma unroll
    for (int j = 0; j < 16; j += 4) {
      ushort4v o;
      o.x = tile[rb + j + 0][cl];
      o.y = tile[rb + j + 1][cl];
      o.z = tile[rb + j + 2][cl];
      o.w = tile[rb + j + 3][cl];
      *(ushort4v*)(dst + j) = o;
    }
  }
}

// -------------------------------------------- 128x128 m97-structure GEMM ---
// A: (E, M, Kz) bf16 row-major; B: (E, N, Kz) bf16 (B^T, K contiguous).
// Out (E,M,N) bf16. BK=32, 4 waves (2x2, 64x64 each), single-buffer 16KB
// LDS, 2 __syncthreads per K-step, plain C++ LDS reads, global_load_lds
// staging with pre-permuted global rows (LDS stays linear, conflict-free
// fragment-major subtiles). NO inline-asm waits / sched_barriers / setprio:
// the compiler schedules (counted lgkmcnt interleave) and ~3 blocks/CU give
// inter-block overlap across barrier drains (m97/m114 recipe).
template <bool GELU>
__global__ __launch_bounds__(256) void gemm128_kernel(
    const unsigned short* __restrict__ A, const unsigned short* __restrict__ B,
    const float* __restrict__ bias, unsigned short* __restrict__ Out, int M,
    int N, int Kz, int NT, int mt, int nt) {
  __shared__ __align__(16) char smem[16384];  // As 8KB | Bs 8KB
  int nwg = gridDim.x;
  int bid = blockIdx.x;
  int swz = (bid & 7) * (nwg >> 3) + (bid >> 3);  // XCD-aware (nwg % 8 == 0)
  int bm = swz % mt;
  int r = swz / mt;
  int bn = r % nt;
  int e = r / nt;

  int tid = threadIdx.x;
  int w = tid >> 6, lane = tid & 63;
  int wm = w >> 1, wn = w & 1;
  int fr = lane & 15, g = lane >> 4;
  size_t Kb = (size_t)Kz * 2;  // row stride, bytes
  const char* Ab = (const char*)A + ((size_t)e * M + (size_t)bm * 128) * Kb;
  const char* Bb = (const char*)B + ((size_t)e * N + (size_t)bn * 128) * Kb;
  // staging: thread loads 16B chunks of rows (w*16+fr) and (64+w*16+fr),
  // k-bytes [g*16, g*16+16). LDS dest linear: subtile row16 *1KB + lane*16.
  size_t roW = (size_t)(w * 16 + fr) * Kb + (size_t)g * 16;
  int l16 = lane * 16;

  auto stage = [&](int kb) {
    const char* a0 = Ab + roW + kb;
    GLOAD_LDS16(a0, smem + (w << 10) + l16);
    GLOAD_LDS16(a0 + 64 * Kb, smem + ((4 + w) << 10) + l16);
    const char* b0 = Bb + roW + kb;
    GLOAD_LDS16(b0, smem + 8192 + (w << 10) + l16);
    GLOAD_LDS16(b0 + 64 * Kb, smem + 8192 + ((4 + w) << 10) + l16);
  };

  f32x4 acc[4][4] = {};

  stage(0);
  for (int t = 0; t < NT; ++t) {
    __syncthreads();  // staged tile visible (compiler drains vmcnt)
    short8v av[4], bv4[4];
#pragma unroll
    for (int m = 0; m < 4; ++m)
      av[m] = *(const short8v*)(smem + ((wm * 4 + m) << 10) + l16);
#pragma unroll
    for (int n = 0; n < 4; ++n)
      bv4[n] = *(const short8v*)(smem + 8192 + ((wn * 4 + n) << 10) + l16);
#pragma unroll
    for (int m = 0; m < 4; ++m)
#pragma unroll
      for (int n = 0; n < 4; ++n)
        acc[m][n] = __builtin_amdgcn_mfma_f32_16x16x32_bf16(av[m], bv4[n],
                                                            acc[m][n], 0, 0, 0);
    __syncthreads();  // all reads done before overwrite
    if (t + 1 < NT) stage((t + 1) * 64);
  }

  // ---- epilogue: bias/GELU -> per-wave LDS bounce (2 halves) -> stores ----
  float bv[4];
#pragma unroll
  for (int n = 0; n < 4; ++n)
    bv[n] = bias[(size_t)e * N + (size_t)bn * 128 + wn * 64 + n * 16 + fr];
  unsigned short* wb = (unsigned short*)(smem + w * 4096);  // [32][64] u16
  unsigned short* Oe = Out + ((size_t)e * M + (size_t)bm * 128 +
                              (size_t)wm * 64) * (size_t)N +
                       (size_t)bn * 128 + (size_t)wn * 64;
#pragma unroll
  for (int h = 0; h < 2; ++h) {
#pragma unroll
    for (int m2 = 0; m2 < 2; ++m2)
#pragma unroll
      for (int n = 0; n < 4; ++n)
#pragma unroll
        for (int j = 0; j < 4; ++j) {
          float v = acc[h * 2 + m2][n][j] + bv[n];
          if (GELU) v = 0.5f * v * (1.0f + erff(v * 0.70710678118654752f));
          wb[(m2 * 16 + g * 4 + j) * 64 + n * 16 + fr] = f2bf(v);
        }
#pragma unroll
    for (int p = 0; p < 4; ++p) {
      int rr = p * 8 + (lane >> 3);
      int ch = lane & 7;
      short8v vv = *(const short8v*)(wb + rr * 64 + ch * 8);
      *(short8v*)(Oe + (size_t)(h * 32 + rr) * N + ch * 8) = vv;
    }
  }
}

// ---------------------------------------------------------------- gather ---
__global__ __launch_bounds__(256) void gather_kernel(
    const unsigned short* __restrict__ obuf, const int2* __restrict__ topi,
    const int2* __restrict__ posmj, const float2* __restrict__ wmaj,
    float* __restrict__ y) {
  int tid = threadIdx.x;
  int w = tid >> 6, lane = tid & 63;
  int t = blockIdx.x * 4 + w;
  int2 pp = posmj[t];
  int2 ii = topi[t];
  float2 ww = wmaj[t];
  float* yr = y + (size_t)t * DDIM;
  const unsigned short* s0 =
      (pp.x < CCAP) ? obuf + ((size_t)ii.x * CPAD + pp.x) * DDIM : nullptr;
  const unsigned short* s1 =
      (pp.y < CCAP) ? obuf + ((size_t)ii.y * CPAD + pp.y) * DDIM : nullptr;
#pragma unroll
  for (int j = 0; j < 4; ++j) {
    int c = j * 64 + lane;
    float ax = 0.f, ay = 0.f, az = 0.f, aw = 0.f;
    if (s0) {
      ushort4v a = *(const ushort4v*)(s0 + (size_t)c * 4);
      ax += ww.x * bf2f(a.x); ay += ww.x * bf2f(a.y);
      az += ww.x * bf2f(a.z); aw += ww.x * bf2f(a.w);
    }
    if (s1) {
      ushort4v b = *(const ushort4v*)(s1 + (size_t)c * 4);
      ax += ww.y * bf2f(b.x); ay += ww.y * bf2f(b.y);
      az += ww.y * bf2f(b.z); aw += ww.y * bf2f(b.w);
    }
    ((float4*)yr)[c] = make_float4(ax, ay, az, aw);
  }
}

// ---------------------------------------------------------------------------
extern "C" void kernel_launch(void* const* d_in, const int* in_sizes, int n_in,
                              void* d_out, int out_size, void* d_ws,
                              size_t ws_size, hipStream_t stream) {
  (void)in_sizes; (void)n_in; (void)out_size; (void)ws_size;
  const float* x = (const float*)d_in[0];
  const float* Wg = (const float*)d_in[1];
  const float* W1 = (const float*)d_in[2];
  const float* b1 = (const float*)d_in[3];
  const float* W2 = (const float*)d_in[4];
  const float* b2 = (const float*)d_in[5];
  float* out = (float*)d_out;

  char* ws = (char*)d_ws;
  size_t off = 0;
  auto alloc = [&](size_t b) {
    char* p = ws + off;
    off += (b + 255) & ~(size_t)255;
    return p;
  };
  unsigned short* ein = (unsigned short*)alloc((size_t)NE * CPAD * DDIM * 2);
  unsigned short* hbuf = (unsigned short*)alloc((size_t)NE * CPAD * HDIM * 2);
  unsigned short* obuf = (unsigned short*)alloc((size_t)NE * CPAD * DDIM * 2);
  unsigned short* w1t = (unsigned short*)alloc((size_t)NE * HDIM * DDIM * 2);
  unsigned short* w2t = (unsigned short*)alloc((size_t)NE * DDIM * HDIM * 2);
  int2* topi = (int2*)alloc(T_TOK * sizeof(int2));
  float2* topv = (float2*)alloc(T_TOK * sizeof(float2));
  int2* posmj = (int2*)alloc(T_TOK * sizeof(int2));
  float2* wmaj = (float2*)alloc(T_TOK * sizeof(float2));
  float* blkimp = (float*)alloc(2048 * NE * sizeof(float));

  transpose_cvt_kernel<<<NE * (DDIM / 64) * (HDIM / 64), 256, 0, stream>>>(
      W1, w1t, DDIM, HDIM);
  transpose_cvt_kernel<<<NE * (HDIM / 64) * (DDIM / 64), 256, 0, stream>>>(
      W2, w2t, HDIM, DDIM);
  router_kernel<<<T_TOK / 4, 256, 0, stream>>>(x, Wg, topi, topv, blkimp);
  dispatch_kernel<<<1, 256, 0, stream>>>(topi, topv, blkimp, posmj, wmaj,
                                         out + (size_t)T_TOK * DDIM);
  scatter_kernel<<<(2 * T_TOK) / 4, 256, 0, stream>>>(x, topi, posmj, ein);

  // gemm1: (E,2304,1024) x (E,4096,1024)^T -> hbuf (E,2304,4096), GELU+b1
  gemm128_kernel<true><<<NE * 18 * 32, 256, 0, stream>>>(
      ein, w1t, b1, hbuf, CPAD, HDIM, DDIM, DDIM / 32, 18, 32);
  // gemm2: (E,2304,4096) x (E,1024,4096)^T -> obuf (E,2304,1024), +b2
  gemm128_kernel<false><<<NE * 18 * 8, 256, 0, stream>>>(
      hbuf, w2t, b2, obuf, CPAD, DDIM, HDIM, HDIM / 32, 18, 8);

  gather_kernel<<<T_TOK / 4, 256, 0, stream>>>(obuf, topi, posmj, wmaj, out);
}

// Round 8
// 856.257 us; speedup vs baseline: 1.0147x; 1.0147x over previous
//
#include <hip/hip_runtime.h>
#include <math.h>

typedef short short8v __attribute__((ext_vector_type(8)));
typedef float f32x4 __attribute__((ext_vector_type(4)));
typedef unsigned short ushort4v __attribute__((ext_vector_type(4)));

#define T_TOK 8192
#define DDIM 1024
#define HDIM 4096
#define NE 8
#define CCAP 2150
#define CPAD 2304   // 18 * 128

__device__ __forceinline__ unsigned short f2bf(float f) {
  union { float f; unsigned u; } a; a.f = f;
  unsigned r = a.u + 0x7fffu + ((a.u >> 16) & 1u);   // RNE
  return (unsigned short)(r >> 16);
}
__device__ __forceinline__ float bf2f(unsigned short h) {
  union { unsigned u; float f; } a; a.u = ((unsigned)h) << 16;
  return a.f;
}

#define GLOAD_LDS16(gp, lp)                                                   \
  __builtin_amdgcn_global_load_lds(                                           \
      (const __attribute__((address_space(1))) void*)(gp),                    \
      (__attribute__((address_space(3))) void*)(lp), 16, 0, 0)

// ---------------------------------------------------------------- router ---
__global__ __launch_bounds__(256) void router_kernel(
    const float* __restrict__ x, const float* __restrict__ Wg,
    int2* __restrict__ topi, float2* __restrict__ topv,
    float* __restrict__ blkimp) {
  __shared__ float wg[NE * DDIM];
  __shared__ float gsh[4][NE];
  int tid = threadIdx.x;
  for (int i = tid; i < NE * DDIM / 4; i += 256)
    ((float4*)wg)[i] = ((const float4*)Wg)[i];
  __syncthreads();
  int w = tid >> 6, lane = tid & 63;
  int t = blockIdx.x * 4 + w;
  const float* xr = x + (size_t)t * DDIM;
  float p[NE] = {0.f, 0.f, 0.f, 0.f, 0.f, 0.f, 0.f, 0.f};
#pragma unroll
  for (int j = 0; j < 16; ++j) {
    float xv = xr[lane + 64 * j];
#pragma unroll
    for (int e = 0; e < NE; ++e)
      p[e] = fmaf(xv, wg[e * DDIM + lane + 64 * j], p[e]);
  }
#pragma unroll
  for (int e = 0; e < NE; ++e) {
#pragma unroll
    for (int off = 32; off > 0; off >>= 1) p[e] += __shfl_xor(p[e], off, 64);
  }
  float mx = p[0];
#pragma unroll
  for (int e = 1; e < NE; ++e) mx = fmaxf(mx, p[e]);
  float g[NE];
  float s = 0.f;
#pragma unroll
  for (int e = 0; e < NE; ++e) { g[e] = expf(p[e] - mx); s += g[e]; }
  float inv = 1.0f / s;
#pragma unroll
  for (int e = 0; e < NE; ++e) g[e] *= inv;
  int i0 = 0; float v0 = g[0];
#pragma unroll
  for (int e = 1; e < NE; ++e) if (g[e] > v0) { v0 = g[e]; i0 = e; }
  int i1 = -1; float v1 = -1.0f;
#pragma unroll
  for (int e = 0; e < NE; ++e)
    if (e != i0 && g[e] > v1) { v1 = g[e]; i1 = e; }
  if (lane == 0) {
    topi[t] = make_int2(i0, i1);
    topv[t] = make_float2(v0, v1);
#pragma unroll
    for (int e = 0; e < NE; ++e) gsh[w][e] = g[e];
  }
  __syncthreads();
  if (tid < NE)
    blkimp[blockIdx.x * NE + tid] =
        gsh[0][tid] + gsh[1][tid] + gsh[2][tid] + gsh[3][tid];
}

// ---------------------------------------------- FCFS dispatch + losses -----
__global__ __launch_bounds__(256) void dispatch_kernel(
    const int2* __restrict__ topi, const float2* __restrict__ topv,
    const float* __restrict__ blkimp, int2* __restrict__ posmj,
    float2* __restrict__ wmaj, float* __restrict__ tail) {
  __shared__ unsigned char eid[2 * T_TOK];
  __shared__ unsigned short possm[2 * T_TOK];
  __shared__ int cnt_sh[NE];
  __shared__ float part[32][NE];
  int tid = threadIdx.x;
  for (int i = tid; i < T_TOK; i += 256) {
    int2 ti = topi[i];
    eid[i] = (unsigned char)ti.x;
    eid[T_TOK + i] = (unsigned char)ti.y;
  }
  __syncthreads();
  if (tid < 64) {
    int lane = tid;
    unsigned long long low = (1ull << lane) - 1ull;
    int c0 = 0, c1 = 0, c2 = 0, c3 = 0, c4 = 0, c5 = 0, c6 = 0, c7 = 0;
    for (int base = 0; base < 2 * T_TOK; base += 64) {
      int e = eid[base + lane];
      unsigned long long m0 = __ballot(e == 0);
      unsigned long long m1 = __ballot(e == 1);
      unsigned long long m2 = __ballot(e == 2);
      unsigned long long m3 = __ballot(e == 3);
      unsigned long long m4 = __ballot(e == 4);
      unsigned long long m5 = __ballot(e == 5);
      unsigned long long m6 = __ballot(e == 6);
      unsigned long long m7 = __ballot(e == 7);
      int rank = 0;
      if (e == 0) rank = c0 + __popcll(m0 & low);
      if (e == 1) rank = c1 + __popcll(m1 & low);
      if (e == 2) rank = c2 + __popcll(m2 & low);
      if (e == 3) rank = c3 + __popcll(m3 & low);
      if (e == 4) rank = c4 + __popcll(m4 & low);
      if (e == 5) rank = c5 + __popcll(m5 & low);
      if (e == 6) rank = c6 + __popcll(m6 & low);
      if (e == 7) rank = c7 + __popcll(m7 & low);
      possm[base + lane] = (unsigned short)((rank < CCAP) ? rank : CCAP);
      c0 += __popcll(m0); c1 += __popcll(m1); c2 += __popcll(m2);
      c3 += __popcll(m3); c4 += __popcll(m4); c5 += __popcll(m5);
      c6 += __popcll(m6); c7 += __popcll(m7);
    }
    if (lane == 0) {
      cnt_sh[0] = c0; cnt_sh[1] = c1; cnt_sh[2] = c2; cnt_sh[3] = c3;
      cnt_sh[4] = c4; cnt_sh[5] = c5; cnt_sh[6] = c6; cnt_sh[7] = c7;
    }
  }
  __syncthreads();
  for (int t = tid; t < T_TOK; t += 256) {
    int p0 = possm[t], p1 = possm[T_TOK + t];
    float2 tv = topv[t];
    float w0 = (p0 < CCAP) ? tv.x : 0.0f;
    float w1 = (p1 < CCAP) ? tv.y : 0.0f;
    float s = w0 + w1;
    if (s > 0.0f) { w0 /= s; w1 /= s; }
    posmj[t] = make_int2(p0, p1);
    wmaj[t] = make_float2(w0, w1);
  }
  {
    int sl = tid >> 3, e8 = tid & 7;
    float s = 0.f;
    for (int b = sl; b < 2048; b += 32) s += blkimp[b * NE + e8];
    part[sl][e8] = s;
  }
  __syncthreads();
  if (tid == 0) {
    float imp[NE], te[NE];
    for (int e = 0; e < NE; ++e) {
      float s = 0.f;
      for (int j = 0; j < 32; ++j) s += part[j][e];
      imp[e] = s;
      int c = cnt_sh[e];
      te[e] = (float)(c < CCAP ? c : CCAP);
    }
    float mi = 0.f, mt = 0.f;
    for (int e = 0; e < NE; ++e) { mi += imp[e]; mt += te[e]; }
    mi *= 0.125f; mt *= 0.125f;
    float vi = 0.f, vt = 0.f;
    for (int e = 0; e < NE; ++e) {
      vi += (imp[e] - mi) * (imp[e] - mi);
      vt += (te[e] - mt) * (te[e] - mt);
    }
    vi *= 0.125f; vt *= 0.125f;
    float ai = sqrtf(vi) / (mi + 1e-6f);
    float at = sqrtf(vt) / (mt + 1e-6f);
    tail[0] = 0.5f * (ai * ai + at * at);
    tail[1] = at * at;
  }
}

// --------------------------------------------------------------- scatter ---
__global__ __launch_bounds__(256) void scatter_kernel(
    const float* __restrict__ x, const int2* __restrict__ topi,
    const int2* __restrict__ posmj, unsigned short* __restrict__ ein) {
  int tid = threadIdx.x;
  int gid = blockIdx.x * 4 + (tid >> 6);
  int lane = tid & 63;
  int t = gid >> 1, k = gid & 1;
  int2 pp = posmj[t];
  int p = k ? pp.y : pp.x;
  if (p >= CCAP) return;
  int2 ii = topi[t];
  int e = k ? ii.y : ii.x;
  const float4* src = (const float4*)(x + (size_t)t * DDIM);
  unsigned short* dst = ein + ((size_t)e * CPAD + p) * DDIM;
#pragma unroll
  for (int j = 0; j < 4; ++j) {
    int c = j * 64 + lane;
    float4 v = src[c];
    ushort4v o;
    o.x = f2bf(v.x); o.y = f2bf(v.y); o.z = f2bf(v.z); o.w = f2bf(v.w);
    *(ushort4v*)(dst + (size_t)c * 4) = o;
  }
}

// ------------------------------------------------- weight transpose+cvt ----
__global__ __launch_bounds__(256) void transpose_cvt_kernel(
    const float* __restrict__ W, unsigned short* __restrict__ WT, int R,
    int Cc) {
  __shared__ unsigned short tile[64][72];
  int rt = R >> 6, ct = Cc >> 6;
  int per_e = rt * ct;
  int e = blockIdx.x / per_e;
  int rem = blockIdx.x % per_e;
  int tr = rem % rt, tc = rem / rt;
  int r0 = tr << 6, c0 = tc << 6;
  const float* We = W + (size_t)e * R * Cc;
  unsigned short* WTe = WT + (size_t)e * R * Cc;
  int tid = threadIdx.x;
  {
    int rl = tid >> 2, cb = (tid & 3) << 4;
    const float* src = We + (size_t)(r0 + rl) * Cc + c0 + cb;
#pragma unroll
    for (int j = 0; j < 16; j += 4) {
      float4 v = *(const float4*)(src + j);
      tile[rl][cb + j + 0] = f2bf(v.x);
      tile[rl][cb + j + 1] = f2bf(v.y);
      tile[rl][cb + j + 2] = f2bf(v.z);
      tile[rl][cb + j + 3] = f2bf(v.w);
    }
  }
  __syncthreads();
  {
    int cl = tid >> 2, rb = (tid & 3) << 4;
    unsigned short* dst = WTe + (size_t)(c0 + cl) * R + r0 + rb;
#pragma unroll
    for (int j = 0; j < 16; j += 4) {
      ushort4v o;
      o.x = tile[rb + j + 0][cl];
      o.y = tile[rb + j + 1][cl];
      o.z = tile[rb + j + 2][cl];
      o.w = tile[rb + j + 3][cl];
      *(ushort4v*)(dst + j) = o;
    }
  }
}

// -------------------------------- 128x128 double-buffered GEMM (2 blk/CU) --
// A: (E, M, Kz) bf16 row-major; B: (E, N, Kz) bf16 (B^T, K contiguous).
// Out (E,M,N) bf16. BK=64, 4 waves (2x2, 64x64/wave), 64KB LDS double
// buffer -> 2 blocks/CU for inter-block phase decorrelation (m114). Plain
// C++ LDS reads + __syncthreads (ONE per K-tile): compiler emits counted
// lgkmcnt for ds_read->MFMA and a vmcnt drain before the barrier, which
// lands AFTER the tile's compute (stage issued first). No inline asm.
// LDS layout [isB:32KB][buf:16KB][kh:8KB][m16:1KB][lane*16] -- fragment-
// major subtiles, wave-linear reads, zero bank conflicts; staging uses
// pre-permuted global rows with linear LDS dests (rule #21 both-sides).
template <bool GELU>
__global__ __launch_bounds__(256) void gemm128_kernel(
    const unsigned short* __restrict__ A, const unsigned short* __restrict__ B,
    const float* __restrict__ bias, unsigned short* __restrict__ Out, int M,
    int N, int Kz, int NT, int mt, int nt) {
  __shared__ __align__(16) char smem[65536];
  int nwg = gridDim.x;
  int bid = blockIdx.x;
  int swz = (bid & 7) * (nwg >> 3) + (bid >> 3);  // XCD-aware (nwg % 8 == 0)
  int bm = swz % mt;                              // bm-inner: B-panel reuse
  int r = swz / mt;
  int bn = r % nt;
  int e = r / nt;

  int tid = threadIdx.x;
  int w = tid >> 6, lane = tid & 63;
  int wm = w >> 1, wn = w & 1;
  int fr = lane & 15, g = lane >> 4;
  size_t Kb = (size_t)Kz * 2;  // row stride in bytes
  const char* Ab = (const char*)A + ((size_t)e * M + (size_t)bm * 128) * Kb;
  const char* Bb = (const char*)B + ((size_t)e * N + (size_t)bn * 128) * Kb;

  // stage one 8KB quarter (tile rows 0-63 or 64-127 of A or B, one kh):
  // thread covers row (j*4+w)*16+fr, k-bytes kh*64 + g*16.
  size_t ro0 = (size_t)(w * 16 + fr) * Kb + (size_t)g * 16;
  size_t ro1 = ro0 + (size_t)64 * Kb;
  int ld0 = (w << 10) + lane * 16;
  int ld1 = ((4 + w) << 10) + lane * 16;
  auto stage = [&](const char* gb, int buf, int isB, int kh) {
    int base = (isB << 15) + (buf << 14) + (kh << 13);
    GLOAD_LDS16(gb + ro0 + kh * 64, smem + base + ld0);
    GLOAD_LDS16(gb + ro1 + kh * 64, smem + base + ld1);
  };
  auto stage_tile = [&](int t, int buf) {
    const char* a = Ab + (size_t)t * 128;  // 64 K-elems = 128 bytes
    const char* b = Bb + (size_t)t * 128;
    stage(a, buf, 0, 0); stage(a, buf, 0, 1);
    stage(b, buf, 1, 0); stage(b, buf, 1, 1);
  };
  auto lda = [&](int buf, int kk, int m) -> short8v {
    return *(const short8v*)(smem + (buf << 14) + (kk << 13) +
                             ((wm * 4 + m) << 10) + lane * 16);
  };
  auto ldb = [&](int buf, int kk, int n) -> short8v {
    return *(const short8v*)(smem + 32768 + (buf << 14) + (kk << 13) +
                             ((wn * 4 + n) << 10) + lane * 16);
  };

  f32x4 acc[4][4] = {};

  stage_tile(0, 0);
  __syncthreads();
  for (int t = 0; t < NT; ++t) {
    int c = t & 1;
    if (t + 1 < NT) stage_tile(t + 1, c ^ 1);  // issue first; lands by barrier
#pragma unroll
    for (int kk = 0; kk < 2; ++kk) {
      short8v av[4], bv4[4];
#pragma unroll
      for (int m = 0; m < 4; ++m) av[m] = lda(c, kk, m);
#pragma unroll
      for (int n = 0; n < 4; ++n) bv4[n] = ldb(c, kk, n);
#pragma unroll
      for (int m = 0; m < 4; ++m)
#pragma unroll
        for (int n = 0; n < 4; ++n)
          acc[m][n] = __builtin_amdgcn_mfma_f32_16x16x32_bf16(
              av[m], bv4[n], acc[m][n], 0, 0, 0);
    }
    __syncthreads();  // one barrier per K-tile (buffers disjoint otherwise)
  }

  // ---- epilogue: bias/GELU -> per-wave LDS bounce -> coalesced stores ----
  float bv[4];
#pragma unroll
  for (int n = 0; n < 4; ++n)
    bv[n] = bias[(size_t)e * N + (size_t)bn * 128 + wn * 64 + n * 16 + fr];
  unsigned short* wb = (unsigned short*)(smem + w * 8192);  // [64][64] u16
#pragma unroll
  for (int m = 0; m < 4; ++m)
#pragma unroll
    for (int n = 0; n < 4; ++n)
#pragma unroll
      for (int j = 0; j < 4; ++j) {
        float v = acc[m][n][j] + bv[n];
        if (GELU) v = 0.5f * v * (1.0f + erff(v * 0.70710678118654752f));
        wb[(m * 16 + g * 4 + j) * 64 + n * 16 + fr] = f2bf(v);
      }
  unsigned short* Oe = Out + ((size_t)e * M + (size_t)bm * 128 +
                              (size_t)wm * 64) * (size_t)N +
                       (size_t)bn * 128 + (size_t)wn * 64;
#pragma unroll
  for (int p = 0; p < 8; ++p) {
    int rr = p * 8 + (lane >> 3);
    int ch = lane & 7;
    short8v vv = *(const short8v*)(wb + rr * 64 + ch * 8);
    *(short8v*)(Oe + (size_t)rr * N + ch * 8) = vv;
  }
}

// ---------------------------------------------------------------- gather ---
__global__ __launch_bounds__(256) void gather_kernel(
    const unsigned short* __restrict__ obuf, const int2* __restrict__ topi,
    const int2* __restrict__ posmj, const float2* __restrict__ wmaj,
    float* __restrict__ y) {
  int tid = threadIdx.x;
  int w = tid >> 6, lane = tid & 63;
  int t = blockIdx.x * 4 + w;
  int2 pp = posmj[t];
  int2 ii = topi[t];
  float2 ww = wmaj[t];
  float* yr = y + (size_t)t * DDIM;
  const unsigned short* s0 =
      (pp.x < CCAP) ? obuf + ((size_t)ii.x * CPAD + pp.x) * DDIM : nullptr;
  const unsigned short* s1 =
      (pp.y < CCAP) ? obuf + ((size_t)ii.y * CPAD + pp.y) * DDIM : nullptr;
#pragma unroll
  for (int j = 0; j < 4; ++j) {
    int c = j * 64 + lane;
    float ax = 0.f, ay = 0.f, az = 0.f, aw = 0.f;
    if (s0) {
      ushort4v a = *(const ushort4v*)(s0 + (size_t)c * 4);
      ax += ww.x * bf2f(a.x); ay += ww.x * bf2f(a.y);
      az += ww.x * bf2f(a.z); aw += ww.x * bf2f(a.w);
    }
    if (s1) {
      ushort4v b = *(const ushort4v*)(s1 + (size_t)c * 4);
      ax += ww.y * bf2f(b.x); ay += ww.y * bf2f(b.y);
      az += ww.y * bf2f(b.z); aw += ww.y * bf2f(b.w);
    }
    ((float4*)yr)[c] = make_float4(ax, ay, az, aw);
  }
}

// ---------------------------------------------------------------------------
extern "C" void kernel_launch(void* const* d_in, const int* in_sizes, int n_in,
                              void* d_out, int out_size, void* d_ws,
                              size_t ws_size, hipStream_t stream) {
  (void)in_sizes; (void)n_in; (void)out_size; (void)ws_size;
  const float* x = (const float*)d_in[0];
  const float* Wg = (const float*)d_in[1];
  const float* W1 = (const float*)d_in[2];
  const float* b1 = (const float*)d_in[3];
  const float* W2 = (const float*)d_in[4];
  const float* b2 = (const float*)d_in[5];
  float* out = (float*)d_out;

  char* ws = (char*)d_ws;
  size_t off = 0;
  auto alloc = [&](size_t b) {
    char* p = ws + off;
    off += (b + 255) & ~(size_t)255;
    return p;
  };
  unsigned short* ein = (unsigned short*)alloc((size_t)NE * CPAD * DDIM * 2);
  unsigned short* hbuf = (unsigned short*)alloc((size_t)NE * CPAD * HDIM * 2);
  unsigned short* obuf = (unsigned short*)alloc((size_t)NE * CPAD * DDIM * 2);
  unsigned short* w1t = (unsigned short*)alloc((size_t)NE * HDIM * DDIM * 2);
  unsigned short* w2t = (unsigned short*)alloc((size_t)NE * DDIM * HDIM * 2);
  int2* topi = (int2*)alloc(T_TOK * sizeof(int2));
  float2* topv = (float2*)alloc(T_TOK * sizeof(float2));
  int2* posmj = (int2*)alloc(T_TOK * sizeof(int2));
  float2* wmaj = (float2*)alloc(T_TOK * sizeof(float2));
  float* blkimp = (float*)alloc(2048 * NE * sizeof(float));

  transpose_cvt_kernel<<<NE * (DDIM / 64) * (HDIM / 64), 256, 0, stream>>>(
      W1, w1t, DDIM, HDIM);
  transpose_cvt_kernel<<<NE * (HDIM / 64) * (DDIM / 64), 256, 0, stream>>>(
      W2, w2t, HDIM, DDIM);
  router_kernel<<<T_TOK / 4, 256, 0, stream>>>(x, Wg, topi, topv, blkimp);
  dispatch_kernel<<<1, 256, 0, stream>>>(topi, topv, blkimp, posmj, wmaj,
                                         out + (size_t)T_TOK * DDIM);
  scatter_kernel<<<(2 * T_TOK) / 4, 256, 0, stream>>>(x, topi, posmj, ein);

  // gemm1: (E,2304,1024) x (E,4096,1024)^T -> hbuf (E,2304,4096), GELU+b1
  gemm128_kernel<true><<<NE * 18 * 32, 256, 0, stream>>>(
      ein, w1t, b1, hbuf, CPAD, HDIM, DDIM, DDIM / 64, 18, 32);
  // gemm2: (E,2304,4096) x (E,1024,4096)^T -> obuf (E,2304,1024), +b2
  gemm128_kernel<false><<<NE * 18 * 8, 256, 0, stream>>>(
      hbuf, w2t, b2, obuf, CPAD, DDIM, HDIM, HDIM / 64, 18, 8);

  gather_kernel<<<T_TOK / 4, 256, 0, stream>>>(obuf, topi, posmj, wmaj, out);
}